// Round 1
// 1326.480 us; speedup vs baseline: 1.4103x; 1.4103x over previous
//
#include <hip/hip_runtime.h>
#include <math.h>

// Mamba single-step recurrence, BATCH=2048.
// GEMMs run on the matrix cores via error-compensated split-bf16:
//   A = Ah + Al (bf16 hi/lo), B = Bh + Bl;  C = Ah*Bh + Al*Bh + Ah*Bl  (fp32 acc)
// Representation error ~2^-18 relative (fp32-equivalent for this tolerance).
//
// Pipeline:
//  C0: split x -> bf16 hi/lo                 C1: transpose+split w_inp -> [N,K]
//  C2: split in_proj_w (already [N,K])       C3: split out_proj_w (already [N,K])
//  K1: h   = x @ w_inp + b_inp      (MFMA, emits h hi/lo)
//  K2: xz  = h @ in_proj_w^T        (MFMA, fp32 out)
//  K3: conv shift+silu -> xc
//  K4: xdb = xc @ x_proj_w^T        (vector, tiny N=96)
//  K5: dt/softplus/SSM/y            (emits y hi/lo)
//  K6: core= y @ out_proj_w^T       (MFMA, emits core hi/lo)
//  C4: transpose+split w_outp -> [N,K]
//  K7: out = core @ w_outp + b_outp (MFMA, fp32 out)

#define BATCH 2048
#define D_INNER 2048
#define D_STATE 16
#define D_CONV 4
#define DT_RANK 64
#define XDB_N 96
#define RNN_ROW 40960

typedef unsigned short u16;
typedef short bf16x8 __attribute__((ext_vector_type(8)));
typedef float f32x4 __attribute__((ext_vector_type(4)));

__device__ __forceinline__ float silu_f(float v) {
    return v / (1.f + __expf(-v));
}

// bf16 round-to-nearest-even, bit-level (no API ambiguity)
__device__ __forceinline__ u16 f2bf(float x) {
    unsigned int u = __float_as_uint(x);
    u += 0x7FFFu + ((u >> 16) & 1u);
    return (u16)(u >> 16);
}
__device__ __forceinline__ float bf2f(u16 b) {
    return __uint_as_float(((unsigned int)b) << 16);
}
__device__ __forceinline__ void split_f(float x, u16& h, u16& l) {
    h = f2bf(x);
    l = f2bf(x - bf2f(h));
}

// async global->LDS, 16B per lane
typedef __attribute__((address_space(1))) const unsigned int guint;
typedef __attribute__((address_space(3))) unsigned int luint;
__device__ __forceinline__ void gload16(const void* g, void* l) {
    __builtin_amdgcn_global_load_lds((guint*)g, (luint*)l, 16, 0, 0);
}

// ---------------------------------------------------------------------------
// Split-bf16 MFMA GEMM: C[M,N] = (Ah+Al)[M,K] @ (Bh+Bl)[N,K]^T (+bias).
// 128x128 tile, BK=32, 256 threads (4 waves), each wave owns a 64x64 quadrant
// as 4x4 fragments of mfma_f32_16x16x32_bf16. Staging via global_load_lds x16B.
// SPLITOUT: emit C as bf16 hi/lo (feeds the next split GEMM's A operand).
// ---------------------------------------------------------------------------
template<bool BIAS, bool SPLITOUT>
__global__ __launch_bounds__(256)
void gemm_mfma(const u16* __restrict__ Ah, const u16* __restrict__ Al,
               const u16* __restrict__ Bh, const u16* __restrict__ Bl,
               const float* __restrict__ bias,
               float* __restrict__ Cf, u16* __restrict__ Ch, u16* __restrict__ Cl,
               int M, int N, int K) {
    __shared__ u16 sA_h[128 * 32];
    __shared__ u16 sA_l[128 * 32];
    __shared__ u16 sB_h[128 * 32];
    __shared__ u16 sB_l[128 * 32];

    const int tid  = threadIdx.x;
    const int wave = tid >> 6;
    const int lane = tid & 63;
    const int l16  = lane & 15;
    const int lsel = lane >> 4;

    // Bijective XCD-aware block swizzle (all our grids have nwg % 8 == 0):
    // consecutive dispatch ids (same XCD) map to contiguous logical tiles.
    int bx = blockIdx.x, by = blockIdx.y;
    {
        const int gx = gridDim.x;
        const int nwg = gx * gridDim.y;
        int bid = by * gx + bx;
        if ((nwg & 7) == 0) {
            bid = (bid & 7) * (nwg >> 3) + (bid >> 3);
            bx = bid % gx;
            by = bid / gx;
        }
    }
    const int m0 = by * 128;
    const int n0 = bx * 128;

    // staging: tile = 128 rows x 32 bf16 (64B/row); 16B chunk c -> row c>>2, col (c&3)*8
    const int c0 = tid, c1 = tid + 256;
    const int sr0 = c0 >> 2, sc0 = (c0 & 3) * 8;
    const int sr1 = c1 >> 2, sc1 = (c1 & 3) * 8;
    const u16* gA0h = Ah + (size_t)(m0 + sr0) * K + sc0;
    const u16* gA1h = Ah + (size_t)(m0 + sr1) * K + sc1;
    const u16* gA0l = Al + (size_t)(m0 + sr0) * K + sc0;
    const u16* gA1l = Al + (size_t)(m0 + sr1) * K + sc1;
    const u16* gB0h = Bh + (size_t)(n0 + sr0) * K + sc0;
    const u16* gB1h = Bh + (size_t)(n0 + sr1) * K + sc1;
    const u16* gB0l = Bl + (size_t)(n0 + sr0) * K + sc0;
    const u16* gB1l = Bl + (size_t)(n0 + sr1) * K + sc1;
    u16* lA0h = &sA_h[c0 * 8]; u16* lA1h = &sA_h[c1 * 8];
    u16* lA0l = &sA_l[c0 * 8]; u16* lA1l = &sA_l[c1 * 8];
    u16* lB0h = &sB_h[c0 * 8]; u16* lB1h = &sB_h[c1 * 8];
    u16* lB0l = &sB_l[c0 * 8]; u16* lB1l = &sB_l[c1 * 8];

    // fragment read bases: wave (wr,wc) quadrant, A row = wr*64+i*16+l16,
    // B row (of B^T) = wc*64+j*16+l16, k offset = lsel*8 (8 contiguous bf16).
    const int arow = (wave >> 1) * 64 + l16;
    const int brow = (wave & 1) * 64 + l16;
    const int kof  = lsel * 8;

    f32x4 acc[4][4];
#pragma unroll
    for (int i = 0; i < 4; ++i)
#pragma unroll
        for (int j = 0; j < 4; ++j) acc[i][j] = f32x4{0.f, 0.f, 0.f, 0.f};

    for (int k0 = 0; k0 < K; k0 += 32) {
        gload16(gA0h + k0, lA0h);
        gload16(gA1h + k0, lA1h);
        gload16(gA0l + k0, lA0l);
        gload16(gA1l + k0, lA1l);
        gload16(gB0h + k0, lB0h);
        gload16(gB1h + k0, lB1h);
        gload16(gB0l + k0, lB0l);
        gload16(gB1l + k0, lB1l);
        asm volatile("s_waitcnt vmcnt(0)" ::: "memory");
        __syncthreads();

        bf16x8 bh[4], bl[4];
#pragma unroll
        for (int j = 0; j < 4; ++j) {
            bh[j] = *(const bf16x8*)&sB_h[(brow + j * 16) * 32 + kof];
            bl[j] = *(const bf16x8*)&sB_l[(brow + j * 16) * 32 + kof];
        }
#pragma unroll
        for (int i = 0; i < 4; ++i) {
            bf16x8 ah = *(const bf16x8*)&sA_h[(arow + i * 16) * 32 + kof];
            bf16x8 al = *(const bf16x8*)&sA_l[(arow + i * 16) * 32 + kof];
#pragma unroll
            for (int j = 0; j < 4; ++j) {
                acc[i][j] = __builtin_amdgcn_mfma_f32_16x16x32_bf16(ah, bh[j], acc[i][j], 0, 0, 0);
                acc[i][j] = __builtin_amdgcn_mfma_f32_16x16x32_bf16(al, bh[j], acc[i][j], 0, 0, 0);
                acc[i][j] = __builtin_amdgcn_mfma_f32_16x16x32_bf16(ah, bl[j], acc[i][j], 0, 0, 0);
            }
        }
        __syncthreads();
    }

    // epilogue: C/D layout col = lane&15, row = (lane>>4)*4 + reg  [m89-verified]
    const int crow = m0 + (wave >> 1) * 64 + lsel * 4;
    const int ccol = n0 + (wave & 1) * 64 + l16;
#pragma unroll
    for (int i = 0; i < 4; ++i) {
#pragma unroll
        for (int j = 0; j < 4; ++j) {
            const int col = ccol + j * 16;
            float bv = 0.f;
            if (BIAS) bv = bias[col];
#pragma unroll
            for (int r = 0; r < 4; ++r) {
                const int row = crow + i * 16 + r;
                float v = acc[i][j][r] + bv;
                if (SPLITOUT) {
                    u16 hh, ll;
                    split_f(v, hh, ll);
                    Ch[(size_t)row * N + col] = hh;
                    Cl[(size_t)row * N + col] = ll;
                } else {
                    Cf[(size_t)row * N + col] = v;
                }
            }
        }
    }
}

// ---------------------------------------------------------------------------
// C-splits: fp32 -> bf16 hi/lo, same layout (vectorized 4 elems/thread)
// ---------------------------------------------------------------------------
__global__ __launch_bounds__(256)
void split_nt(const float* __restrict__ W, u16* __restrict__ H, u16* __restrict__ L, int n4) {
    const int i = blockIdx.x * 256 + threadIdx.x;
    if (i >= n4) return;
    float4 v = ((const float4*)W)[i];
    u16 h0, l0, h1, l1, h2, l2, h3, l3;
    split_f(v.x, h0, l0); split_f(v.y, h1, l1);
    split_f(v.z, h2, l2); split_f(v.w, h3, l3);
    ushort4 hv; hv.x = h0; hv.y = h1; hv.z = h2; hv.w = h3;
    ushort4 lv; lv.x = l0; lv.y = l1; lv.z = l2; lv.w = l3;
    *(ushort4*)&H[(size_t)i * 4] = hv;
    *(ushort4*)&L[(size_t)i * 4] = lv;
}

// fp32 W[K][N] -> bf16 hi/lo [N][K] (transpose via 32x33 LDS tile)
__global__ __launch_bounds__(256)
void split_t(const float* __restrict__ W, u16* __restrict__ H, u16* __restrict__ L,
             int K, int N) {
    __shared__ float t[32][33];
    const int n0 = blockIdx.x * 32;
    const int k0 = blockIdx.y * 32;
    const int tx = threadIdx.x & 31;
    const int ty = threadIdx.x >> 5;   // 0..7
#pragma unroll
    for (int s = 0; s < 32; s += 8)
        t[ty + s][tx] = W[(size_t)(k0 + ty + s) * N + n0 + tx];
    __syncthreads();
#pragma unroll
    for (int s = 0; s < 32; s += 8) {
        float v = t[tx][ty + s];
        u16 h, l;
        split_f(v, h, l);
        H[(size_t)(n0 + ty + s) * K + k0 + tx] = h;
        L[(size_t)(n0 + ty + s) * K + k0 + tx] = l;
    }
}

// ---------------------------------------------------------------------------
// K3: conv state shift + depthwise conv + silu. One thread per (b,d).
// ---------------------------------------------------------------------------
__global__ __launch_bounds__(256)
void conv_kernel(const float* __restrict__ rnn_in, const float* __restrict__ xz,
                 const float* __restrict__ conv_w, const float* __restrict__ conv_b,
                 float* __restrict__ xc, float* __restrict__ rnn_out) {
    const int idx = blockIdx.x * 256 + threadIdx.x;   // b*2048 + d
    const int b = idx >> 11;
    const int d = idx & 2047;
    const size_t off = (size_t)b * RNN_ROW + (size_t)d * 20;
    float4 cs = *(const float4*)&rnn_in[off];
    const float xi = xz[(size_t)b * 4096 + d];
    float4 w = *(const float4*)&conv_w[d * 4];
    float pre = cs.y * w.x + cs.z * w.y + cs.w * w.z + xi * w.w + conv_b[d];
    xc[idx] = silu_f(pre);
    float4 ns = make_float4(cs.y, cs.z, cs.w, xi);
    *(float4*)&rnn_out[off] = ns;
}

// ---------------------------------------------------------------------------
// K4: xdb[b][n] = sum_k xc[b][k]*x_proj_w[n][k], n<96.
// ---------------------------------------------------------------------------
__global__ __launch_bounds__(256)
void xproj_kernel(const float* __restrict__ xc, const float* __restrict__ xw,
                  float* __restrict__ xdb) {
    __shared__ float xs[8][256];
    const int tid = threadIdx.x;
    const int b0 = blockIdx.x * 8;
    const int r = tid >> 5;
    const int lane = tid & 31;
    float acc0 = 0.f, acc1 = 0.f, acc2 = 0.f;
    for (int k0 = 0; k0 < 2048; k0 += 256) {
        __syncthreads();
        for (int l = tid; l < 8 * 256; l += 256) {
            int row = l >> 8, c = l & 255;
            xs[row][c] = xc[(size_t)(b0 + row) * 2048 + k0 + c];
        }
        __syncthreads();
#pragma unroll 4
        for (int k = 0; k < 256; k += 4) {
            float4 xv = *(const float4*)&xs[r][k];
            float4 w0 = *(const float4*)&xw[(size_t)lane * 2048 + k0 + k];
            float4 w1 = *(const float4*)&xw[(size_t)(lane + 32) * 2048 + k0 + k];
            float4 w2 = *(const float4*)&xw[(size_t)(lane + 64) * 2048 + k0 + k];
            acc0 = fmaf(xv.x, w0.x, fmaf(xv.y, w0.y, fmaf(xv.z, w0.z, fmaf(xv.w, w0.w, acc0))));
            acc1 = fmaf(xv.x, w1.x, fmaf(xv.y, w1.y, fmaf(xv.z, w1.z, fmaf(xv.w, w1.w, acc1))));
            acc2 = fmaf(xv.x, w2.x, fmaf(xv.y, w2.y, fmaf(xv.z, w2.z, fmaf(xv.w, w2.w, acc2))));
        }
    }
    xdb[(size_t)(b0 + r) * XDB_N + lane] = acc0;
    xdb[(size_t)(b0 + r) * XDB_N + lane + 32] = acc1;
    xdb[(size_t)(b0 + r) * XDB_N + lane + 64] = acc2;
}

// ---------------------------------------------------------------------------
// K5: fused dt GEMM (K=64) + softplus + SSM update + y = (s.C + D*xc)*silu(z).
// y emitted as bf16 hi/lo (A-operand of K6's split GEMM).
// ---------------------------------------------------------------------------
__global__ __launch_bounds__(128)
void ssm_kernel(const float* __restrict__ rnn_in, const float* __restrict__ xdb,
                const float* __restrict__ xc, const float* __restrict__ xz,
                const float* __restrict__ dt_w, const float* __restrict__ dt_b,
                const float* __restrict__ A_log, const float* __restrict__ Dp,
                u16* __restrict__ y_h, u16* __restrict__ y_l,
                float* __restrict__ rnn_out) {
    __shared__ float dtw_s[128][65];
    __shared__ float xdb_s[XDB_N];
    const int tid = threadIdx.x;
    const int d0 = blockIdx.x * 128;
    const int b0 = blockIdx.y * 32;
    const int d = d0 + tid;

    for (int l = tid; l < 128 * DT_RANK; l += 128) {
        int dd = l >> 6, r = l & 63;
        dtw_s[dd][r] = dt_w[(size_t)(d0 + dd) * DT_RANK + r];
    }
    float A_row[16];
#pragma unroll
    for (int s = 0; s < 16; ++s) A_row[s] = -__expf(A_log[(size_t)d * 16 + s]);
    const float D_d = Dp[d];
    const float dtb_d = dt_b[d];
    __syncthreads();

    for (int bi = 0; bi < 32; ++bi) {
        const int b = b0 + bi;
        if (tid < XDB_N) xdb_s[tid] = xdb[(size_t)b * XDB_N + tid];
        __syncthreads();

        float acc = dtb_d;
#pragma unroll
        for (int r = 0; r < DT_RANK; ++r) acc = fmaf(xdb_s[r], dtw_s[tid][r], acc);
        const float dt = (acc > 20.f) ? acc : log1pf(__expf(acc));
        const float xc_v = xc[(size_t)b * 2048 + d];
        const float z_v = xz[(size_t)b * 4096 + 2048 + d];
        const float dtxc = dt * xc_v;

        const size_t soff = (size_t)b * RNN_ROW + (size_t)d * 20 + 4;
        float st[16];
        *(float4*)&st[0]  = *(const float4*)&rnn_in[soff + 0];
        *(float4*)&st[4]  = *(const float4*)&rnn_in[soff + 4];
        *(float4*)&st[8]  = *(const float4*)&rnn_in[soff + 8];
        *(float4*)&st[12] = *(const float4*)&rnn_in[soff + 12];

        float y_acc = D_d * xc_v;
#pragma unroll
        for (int s = 0; s < 16; ++s) {
            float Bv = xdb_s[DT_RANK + s];
            float Cv = xdb_s[DT_RANK + 16 + s];
            float ns = fmaf(st[s], __expf(dt * A_row[s]), dtxc * Bv);
            st[s] = ns;
            y_acc = fmaf(ns, Cv, y_acc);
        }
        *(float4*)&rnn_out[soff + 0]  = *(const float4*)&st[0];
        *(float4*)&rnn_out[soff + 4]  = *(const float4*)&st[4];
        *(float4*)&rnn_out[soff + 8]  = *(const float4*)&st[8];
        *(float4*)&rnn_out[soff + 12] = *(const float4*)&st[12];

        const float yv = y_acc * silu_f(z_v);
        u16 hh, ll;
        split_f(yv, hh, ll);
        const size_t yo = (size_t)b * 2048 + d;
        y_h[yo] = hh;
        y_l[yo] = ll;
        __syncthreads();
    }
}

// ---------------------------------------------------------------------------
extern "C" void kernel_launch(void* const* d_in, const int* in_sizes, int n_in,
                              void* d_out, int out_size, void* d_ws, size_t ws_size,
                              hipStream_t stream) {
    const float* x         = (const float*)d_in[0];
    const float* rnn_in    = (const float*)d_in[1];
    const float* w_inp     = (const float*)d_in[2];
    const float* b_inp     = (const float*)d_in[3];
    const float* w_outp    = (const float*)d_in[4];
    const float* b_outp    = (const float*)d_in[5];
    const float* in_proj_w = (const float*)d_in[6];
    const float* conv_w    = (const float*)d_in[7];
    const float* conv_b    = (const float*)d_in[8];
    const float* x_proj_w  = (const float*)d_in[9];
    const float* dt_w      = (const float*)d_in[10];
    const float* dt_b      = (const float*)d_in[11];
    const float* A_log     = (const float*)d_in[12];
    const float* Dp        = (const float*)d_in[13];
    const float* out_proj_w= (const float*)d_in[14];

    float* out_main = (float*)d_out;                       // 2048*512
    float* rnn_out  = (float*)d_out + (size_t)BATCH * 512; // 2048*40960

    // Workspace layout (float offsets; peak = 19,070,976 floats, same as before).
    // Lifetimes:  xz K2..K5 | region1: in_proj(split..K2) -> xc(K3..K5) -> core(K6..K7)
    //             region2: h(K1..K2)+x(..K1)+w_inp_t(..K1) -> y(K5..K6) -> w_outp_t(..K7)
    //             out_proj: split..K6 | xdb: K4..K5
    float* ws = (float*)d_ws;
    float* xz     = ws;                                // [0, 8388608)
    u16*   ip_h   = (u16*)(ws + 8388608);              // 4,194,304 u16
    u16*   ip_l   = ip_h + 4194304;
    float* xc     = ws + 8388608;                      // reuse after K2
    u16*   core_h = (u16*)(ws + 8388608);              // reuse after K5
    u16*   core_l = core_h + 2097152;
    u16*   h_h    = (u16*)(ws + 12582912);
    u16*   h_l    = h_h + 2097152;
    u16*   x_h    = (u16*)(ws + 14680064);
    u16*   x_l    = x_h + 1048576;
    u16*   wi_h   = (u16*)(ws + 15728640);
    u16*   wi_l   = wi_h + 524288;
    u16*   y_h    = (u16*)(ws + 12582912);             // reuse after K2 (h,x,wi dead)
    u16*   y_l    = y_h + 4194304;
    u16*   op_h   = (u16*)(ws + 16777216);
    u16*   op_l   = op_h + 2097152;
    u16*   wo_h   = (u16*)(ws + 12582912);             // reuse after K6 (y dead)
    u16*   wo_l   = wo_h + 524288;
    float* xdb    = ws + 18874368;                     // 196,608

    // C0..C3: weight/input splits
    split_nt<<<1024, 256, 0, stream>>>(x, x_h, x_l, 262144);                 // 2048*512
    split_t <<<dim3(32, 16), 256, 0, stream>>>(w_inp, wi_h, wi_l, 512, 1024);
    split_nt<<<4096, 256, 0, stream>>>(in_proj_w, ip_h, ip_l, 1048576);      // 4096*1024
    split_nt<<<2048, 256, 0, stream>>>(out_proj_w, op_h, op_l, 524288);      // 1024*2048

    // K1: h = x @ w_inp + b_inp  -> h hi/lo
    gemm_mfma<true, true><<<dim3(8, 16), 256, 0, stream>>>(
        x_h, x_l, wi_h, wi_l, b_inp, nullptr, h_h, h_l, BATCH, 1024, 512);
    // K2: xz = h @ in_proj_w^T  -> fp32
    gemm_mfma<false, false><<<dim3(32, 16), 256, 0, stream>>>(
        h_h, h_l, ip_h, ip_l, nullptr, xz, nullptr, nullptr, BATCH, 4096, 1024);
    // K3: conv
    conv_kernel<<<(BATCH * D_INNER) / 256, 256, 0, stream>>>(
        rnn_in, xz, conv_w, conv_b, xc, rnn_out);
    // K4: xdb = xc @ x_proj_w^T
    xproj_kernel<<<BATCH / 8, 256, 0, stream>>>(xc, x_proj_w, xdb);
    // K5: ssm -> y hi/lo
    ssm_kernel<<<dim3(D_INNER / 128, BATCH / 32), 128, 0, stream>>>(
        rnn_in, xdb, xc, xz, dt_w, dt_b, A_log, Dp, y_h, y_l, rnn_out);
    // K6: core = y @ out_proj_w^T -> core hi/lo
    gemm_mfma<false, true><<<dim3(8, 16), 256, 0, stream>>>(
        y_h, y_l, op_h, op_l, nullptr, nullptr, core_h, core_l, BATCH, 1024, 2048);
    // C4: w_outp transpose+split (y region is dead now)
    split_t<<<dim3(16, 32), 256, 0, stream>>>(w_outp, wo_h, wo_l, 1024, 512);
    // K7: out = core @ w_outp + b_outp -> fp32
    gemm_mfma<true, false><<<dim3(4, 16), 256, 0, stream>>>(
        core_h, core_l, wo_h, wo_l, b_outp, out_main, nullptr, nullptr, BATCH, 512, 1024);
}

// Round 2
// 1210.148 us; speedup vs baseline: 1.5459x; 1.0961x over previous
//
#include <hip/hip_runtime.h>
#include <math.h>

// Mamba single-step recurrence, BATCH=2048.
// GEMMs run on the matrix cores via error-compensated split-bf16:
//   A = Ah + Al (bf16 hi/lo), B = Bh + Bl;  C = Ah*Bh + Al*Bh + Ah*Bl  (fp32 acc)
//
// Round 2 changes:
//  - gemm_mfma: double-buffered LDS with prefetch (stage(t+1) overlapped with
//    MFMA(t), ONE barrier per K-step), XOR chunk-swizzle (slot ^= (row>>1)&3)
//    applied on global source + LDS read -> conflict-free ds_read_b128.
//  - ssm2: fully parallel, one thread per (b,d); dt dot folded in; writes the
//    FULL 80B state row (conv shift + ssm) -> dense full-line writes, no RMW.
//  - conv_kernel no longer writes rnn_out (ssm2 does).

#define BATCH 2048
#define D_INNER 2048
#define D_STATE 16
#define D_CONV 4
#define DT_RANK 64
#define XDB_N 96
#define RNN_ROW 40960

typedef unsigned short u16;
typedef short bf16x8 __attribute__((ext_vector_type(8)));
typedef float f32x4 __attribute__((ext_vector_type(4)));

__device__ __forceinline__ float silu_f(float v) {
    return v / (1.f + __expf(-v));
}

// bf16 round-to-nearest-even, bit-level
__device__ __forceinline__ u16 f2bf(float x) {
    unsigned int u = __float_as_uint(x);
    u += 0x7FFFu + ((u >> 16) & 1u);
    return (u16)(u >> 16);
}
__device__ __forceinline__ float bf2f(u16 b) {
    return __uint_as_float(((unsigned int)b) << 16);
}
__device__ __forceinline__ void split_f(float x, u16& h, u16& l) {
    h = f2bf(x);
    l = f2bf(x - bf2f(h));
}

// async global->LDS, 16B per lane
typedef __attribute__((address_space(1))) const unsigned int guint;
typedef __attribute__((address_space(3))) unsigned int luint;
__device__ __forceinline__ void gload16(const void* g, void* l) {
    __builtin_amdgcn_global_load_lds((guint*)g, (luint*)l, 16, 0, 0);
}

// ---------------------------------------------------------------------------
// Split-bf16 MFMA GEMM: C[M,N] = (Ah+Al)[M,K] @ (Bh+Bl)[N,K]^T (+bias).
// 128x128 tile, BK=32, 256 threads (4 waves), 4x4 frags of 16x16x32 per wave.
// Double-buffered LDS (64KB), prefetch of tile t+1 overlaps MFMA of tile t,
// single barrier per K-step (its implicit vmcnt(0) drain is the wait).
// LDS tile rows are 4 chunks of 16B; chunk slot s holds logical chunk
// s ^ ((row>>1)&3)  (involution; applied on source addr AND read addr) ->
// ds_read_b128 lands 2 lanes/bank-group = conflict-free.
// ---------------------------------------------------------------------------
template<bool BIAS, bool SPLITOUT>
__global__ __launch_bounds__(256)
void gemm_mfma(const u16* __restrict__ Ah, const u16* __restrict__ Al,
               const u16* __restrict__ Bh, const u16* __restrict__ Bl,
               const float* __restrict__ bias,
               float* __restrict__ Cf, u16* __restrict__ Ch, u16* __restrict__ Cl,
               int M, int N, int K) {
    __shared__ u16 sA_h[2][128 * 32];
    __shared__ u16 sA_l[2][128 * 32];
    __shared__ u16 sB_h[2][128 * 32];
    __shared__ u16 sB_l[2][128 * 32];

    const int tid  = threadIdx.x;
    const int wave = tid >> 6;
    const int lane = tid & 63;
    const int l16  = lane & 15;
    const int lsel = lane >> 4;

    // Bijective XCD-aware block swizzle (all grids have nwg % 8 == 0).
    int bx = blockIdx.x, by = blockIdx.y;
    {
        const int gx = gridDim.x;
        const int nwg = gx * gridDim.y;
        int bid = by * gx + bx;
        if ((nwg & 7) == 0) {
            bid = (bid & 7) * (nwg >> 3) + (bid >> 3);
            bx = bid % gx;
            by = bid / gx;
        }
    }
    const int m0 = by * 128;
    const int n0 = bx * 128;

    // staging: 128 rows x 32 bf16 (4 slots of 16B per row), LDS dest LINEAR in
    // chunk index; global source column chunk is XOR-swizzled.
    const int c0 = tid, c1 = tid + 256;
    const int sr0 = c0 >> 2, ss0 = ((c0 & 3) ^ ((sr0 >> 1) & 3)) * 8;
    const int sr1 = c1 >> 2, ss1 = ((c1 & 3) ^ ((sr1 >> 1) & 3)) * 8;
    const u16* gA0h = Ah + (size_t)(m0 + sr0) * K + ss0;
    const u16* gA1h = Ah + (size_t)(m0 + sr1) * K + ss1;
    const u16* gA0l = Al + (size_t)(m0 + sr0) * K + ss0;
    const u16* gA1l = Al + (size_t)(m0 + sr1) * K + ss1;
    const u16* gB0h = Bh + (size_t)(n0 + sr0) * K + ss0;
    const u16* gB1h = Bh + (size_t)(n0 + sr1) * K + ss1;
    const u16* gB0l = Bl + (size_t)(n0 + sr0) * K + ss0;
    const u16* gB1l = Bl + (size_t)(n0 + sr1) * K + ss1;
    const int l0 = c0 * 8, l1 = c1 * 8;  // u16 offsets (linear chunk layout)

    // fragment read bases; swz picks the slot holding logical k-chunk lsel
    const int arow = (wave >> 1) * 64 + l16;
    const int brow = (wave & 1) * 64 + l16;
    const int swz  = (lsel ^ ((l16 >> 1) & 3)) * 8;

    f32x4 acc[4][4];
#pragma unroll
    for (int i = 0; i < 4; ++i)
#pragma unroll
        for (int j = 0; j < 4; ++j) acc[i][j] = f32x4{0.f, 0.f, 0.f, 0.f};

    auto stage = [&](int buf, int k0) {
        gload16(gA0h + k0, &sA_h[buf][l0]);
        gload16(gA1h + k0, &sA_h[buf][l1]);
        gload16(gA0l + k0, &sA_l[buf][l0]);
        gload16(gA1l + k0, &sA_l[buf][l1]);
        gload16(gB0h + k0, &sB_h[buf][l0]);
        gload16(gB1h + k0, &sB_h[buf][l1]);
        gload16(gB0l + k0, &sB_l[buf][l0]);
        gload16(gB1l + k0, &sB_l[buf][l1]);
    };

    int cur = 0;
    stage(0, 0);
    for (int k0 = 0; k0 < K; k0 += 32) {
        __syncthreads();                       // drains vmcnt -> buf[cur] ready
        if (k0 + 32 < K) stage(cur ^ 1, k0 + 32);  // prefetch overlaps MFMA

        bf16x8 bh[4], bl[4];
#pragma unroll
        for (int j = 0; j < 4; ++j) {
            bh[j] = *(const bf16x8*)&sB_h[cur][(brow + j * 16) * 32 + swz];
            bl[j] = *(const bf16x8*)&sB_l[cur][(brow + j * 16) * 32 + swz];
        }
#pragma unroll
        for (int i = 0; i < 4; ++i) {
            bf16x8 ah = *(const bf16x8*)&sA_h[cur][(arow + i * 16) * 32 + swz];
            bf16x8 al = *(const bf16x8*)&sA_l[cur][(arow + i * 16) * 32 + swz];
#pragma unroll
            for (int j = 0; j < 4; ++j) {
                acc[i][j] = __builtin_amdgcn_mfma_f32_16x16x32_bf16(ah, bh[j], acc[i][j], 0, 0, 0);
                acc[i][j] = __builtin_amdgcn_mfma_f32_16x16x32_bf16(al, bh[j], acc[i][j], 0, 0, 0);
                acc[i][j] = __builtin_amdgcn_mfma_f32_16x16x32_bf16(ah, bl[j], acc[i][j], 0, 0, 0);
            }
        }
        cur ^= 1;
    }

    // epilogue: C/D layout col = lane&15, row = (lane>>4)*4 + reg
    const int crow = m0 + (wave >> 1) * 64 + lsel * 4;
    const int ccol = n0 + (wave & 1) * 64 + l16;
#pragma unroll
    for (int i = 0; i < 4; ++i) {
#pragma unroll
        for (int j = 0; j < 4; ++j) {
            const int col = ccol + j * 16;
            float bv = 0.f;
            if (BIAS) bv = bias[col];
#pragma unroll
            for (int r = 0; r < 4; ++r) {
                const int row = crow + i * 16 + r;
                float v = acc[i][j][r] + bv;
                if (SPLITOUT) {
                    u16 hh, ll;
                    split_f(v, hh, ll);
                    Ch[(size_t)row * N + col] = hh;
                    Cl[(size_t)row * N + col] = ll;
                } else {
                    Cf[(size_t)row * N + col] = v;
                }
            }
        }
    }
}

// ---------------------------------------------------------------------------
// fp32 -> bf16 hi/lo splits
// ---------------------------------------------------------------------------
__global__ __launch_bounds__(256)
void split_nt(const float* __restrict__ W, u16* __restrict__ H, u16* __restrict__ L, int n4) {
    const int i = blockIdx.x * 256 + threadIdx.x;
    if (i >= n4) return;
    float4 v = ((const float4*)W)[i];
    u16 h0, l0, h1, l1, h2, l2, h3, l3;
    split_f(v.x, h0, l0); split_f(v.y, h1, l1);
    split_f(v.z, h2, l2); split_f(v.w, h3, l3);
    ushort4 hv; hv.x = h0; hv.y = h1; hv.z = h2; hv.w = h3;
    ushort4 lv; lv.x = l0; lv.y = l1; lv.z = l2; lv.w = l3;
    *(ushort4*)&H[(size_t)i * 4] = hv;
    *(ushort4*)&L[(size_t)i * 4] = lv;
}

// fp32 W[K][N] -> bf16 hi/lo [N][K] (transpose via 32x33 LDS tile)
__global__ __launch_bounds__(256)
void split_t(const float* __restrict__ W, u16* __restrict__ H, u16* __restrict__ L,
             int K, int N) {
    __shared__ float t[32][33];
    const int n0 = blockIdx.x * 32;
    const int k0 = blockIdx.y * 32;
    const int tx = threadIdx.x & 31;
    const int ty = threadIdx.x >> 5;   // 0..7
#pragma unroll
    for (int s = 0; s < 32; s += 8)
        t[ty + s][tx] = W[(size_t)(k0 + ty + s) * N + n0 + tx];
    __syncthreads();
#pragma unroll
    for (int s = 0; s < 32; s += 8) {
        float v = t[tx][ty + s];
        u16 h, l;
        split_f(v, h, l);
        H[(size_t)(n0 + ty + s) * K + k0 + tx] = h;
        L[(size_t)(n0 + ty + s) * K + k0 + tx] = l;
    }
}

// ---------------------------------------------------------------------------
// K3: depthwise conv + silu -> xc only (state write moved into ssm2)
// ---------------------------------------------------------------------------
__global__ __launch_bounds__(256)
void conv_kernel(const float* __restrict__ rnn_in, const float* __restrict__ xz,
                 const float* __restrict__ conv_w, const float* __restrict__ conv_b,
                 float* __restrict__ xc) {
    const int idx = blockIdx.x * 256 + threadIdx.x;   // b*2048 + d
    const int b = idx >> 11;
    const int d = idx & 2047;
    const size_t off = (size_t)b * RNN_ROW + (size_t)d * 20;
    float4 cs = *(const float4*)&rnn_in[off];
    const float xi = xz[(size_t)b * 4096 + d];
    float4 w = *(const float4*)&conv_w[d * 4];
    float pre = cs.y * w.x + cs.z * w.y + cs.w * w.z + xi * w.w + conv_b[d];
    xc[idx] = silu_f(pre);
}

// ---------------------------------------------------------------------------
// K4: xdb[b][n] = sum_k xc[b][k]*x_proj_w[n][k], n<96.
// ---------------------------------------------------------------------------
__global__ __launch_bounds__(256)
void xproj_kernel(const float* __restrict__ xc, const float* __restrict__ xw,
                  float* __restrict__ xdb) {
    __shared__ float xs[8][256];
    const int tid = threadIdx.x;
    const int b0 = blockIdx.x * 8;
    const int r = tid >> 5;
    const int lane = tid & 31;
    float acc0 = 0.f, acc1 = 0.f, acc2 = 0.f;
    for (int k0 = 0; k0 < 2048; k0 += 256) {
        __syncthreads();
        for (int l = tid; l < 8 * 256; l += 256) {
            int row = l >> 8, c = l & 255;
            xs[row][c] = xc[(size_t)(b0 + row) * 2048 + k0 + c];
        }
        __syncthreads();
#pragma unroll 4
        for (int k = 0; k < 256; k += 4) {
            float4 xv = *(const float4*)&xs[r][k];
            float4 w0 = *(const float4*)&xw[(size_t)lane * 2048 + k0 + k];
            float4 w1 = *(const float4*)&xw[(size_t)(lane + 32) * 2048 + k0 + k];
            float4 w2 = *(const float4*)&xw[(size_t)(lane + 64) * 2048 + k0 + k];
            acc0 = fmaf(xv.x, w0.x, fmaf(xv.y, w0.y, fmaf(xv.z, w0.z, fmaf(xv.w, w0.w, acc0))));
            acc1 = fmaf(xv.x, w1.x, fmaf(xv.y, w1.y, fmaf(xv.z, w1.z, fmaf(xv.w, w1.w, acc1))));
            acc2 = fmaf(xv.x, w2.x, fmaf(xv.y, w2.y, fmaf(xv.z, w2.z, fmaf(xv.w, w2.w, acc2))));
        }
    }
    xdb[(size_t)(b0 + r) * XDB_N + lane] = acc0;
    xdb[(size_t)(b0 + r) * XDB_N + lane + 32] = acc1;
    xdb[(size_t)(b0 + r) * XDB_N + lane + 64] = acc2;
}

// ---------------------------------------------------------------------------
// K5 (ssm2): fully parallel, one thread per (b,d). Block = one batch x 256 d.
// dt = softplus(xdb[b,:64].dt_w[d] + dt_b[d]) folded in (dt_w is L2-resident).
// Reads the full 80B state row, writes the full 80B row (conv shift + ssm):
// dense full-line traffic, no partial-line RMW. Emits y as bf16 hi/lo.
// ---------------------------------------------------------------------------
__global__ __launch_bounds__(256)
void ssm2_kernel(const float* __restrict__ rnn_in, const float* __restrict__ xdb,
                 const float* __restrict__ xc, const float* __restrict__ xz,
                 const float* __restrict__ dt_w, const float* __restrict__ dt_b,
                 const float* __restrict__ A_log, const float* __restrict__ Dp,
                 u16* __restrict__ y_h, u16* __restrict__ y_l,
                 float* __restrict__ rnn_out) {
    __shared__ float xs[XDB_N];
    const int tid = threadIdx.x;
    const int d = blockIdx.x * 256 + tid;
    const int b = blockIdx.y;
    if (tid < XDB_N) xs[tid] = xdb[(size_t)b * XDB_N + tid];
    __syncthreads();

    // dt (K=64 dot against broadcast xs; dt_w row per thread, L2-cached)
    float acc = dt_b[d];
#pragma unroll
    for (int k = 0; k < 64; k += 4) {
        float4 w = *(const float4*)&dt_w[(size_t)d * 64 + k];
        acc = fmaf(xs[k], w.x, fmaf(xs[k + 1], w.y,
              fmaf(xs[k + 2], w.z, fmaf(xs[k + 3], w.w, acc))));
    }
    const float dt = (acc > 20.f) ? acc : log1pf(__expf(acc));

    const float xc_v = xc[(size_t)b * 2048 + d];
    const float xi   = xz[(size_t)b * 4096 + d];
    const float z_v  = xz[(size_t)b * 4096 + 2048 + d];
    const float dtxc = dt * xc_v;

    const size_t off = (size_t)b * RNN_ROW + (size_t)d * 20;
    float st[20];
    *(float4*)&st[0]  = *(const float4*)&rnn_in[off + 0];
    *(float4*)&st[4]  = *(const float4*)&rnn_in[off + 4];
    *(float4*)&st[8]  = *(const float4*)&rnn_in[off + 8];
    *(float4*)&st[12] = *(const float4*)&rnn_in[off + 12];
    *(float4*)&st[16] = *(const float4*)&rnn_in[off + 16];

    float al[16];
    *(float4*)&al[0]  = *(const float4*)&A_log[(size_t)d * 16 + 0];
    *(float4*)&al[4]  = *(const float4*)&A_log[(size_t)d * 16 + 4];
    *(float4*)&al[8]  = *(const float4*)&A_log[(size_t)d * 16 + 8];
    *(float4*)&al[12] = *(const float4*)&A_log[(size_t)d * 16 + 12];

    float out[20];
    out[0] = st[1]; out[1] = st[2]; out[2] = st[3]; out[3] = xi;
    float y_acc = Dp[d] * xc_v;
#pragma unroll
    for (int s = 0; s < 16; ++s) {
        float ns = fmaf(st[4 + s], __expf(dt * -__expf(al[s])), dtxc * xs[DT_RANK + s]);
        out[4 + s] = ns;
        y_acc = fmaf(ns, xs[DT_RANK + 16 + s], y_acc);
    }
    *(float4*)&rnn_out[off + 0]  = *(const float4*)&out[0];
    *(float4*)&rnn_out[off + 4]  = *(const float4*)&out[4];
    *(float4*)&rnn_out[off + 8]  = *(const float4*)&out[8];
    *(float4*)&rnn_out[off + 12] = *(const float4*)&out[12];
    *(float4*)&rnn_out[off + 16] = *(const float4*)&out[16];

    const float yv = y_acc * silu_f(z_v);
    u16 hh, ll;
    split_f(yv, hh, ll);
    const size_t yo = (size_t)b * 2048 + d;
    y_h[yo] = hh;
    y_l[yo] = ll;
}

// ---------------------------------------------------------------------------
extern "C" void kernel_launch(void* const* d_in, const int* in_sizes, int n_in,
                              void* d_out, int out_size, void* d_ws, size_t ws_size,
                              hipStream_t stream) {
    const float* x         = (const float*)d_in[0];
    const float* rnn_in    = (const float*)d_in[1];
    const float* w_inp     = (const float*)d_in[2];
    const float* b_inp     = (const float*)d_in[3];
    const float* w_outp    = (const float*)d_in[4];
    const float* b_outp    = (const float*)d_in[5];
    const float* in_proj_w = (const float*)d_in[6];
    const float* conv_w    = (const float*)d_in[7];
    const float* conv_b    = (const float*)d_in[8];
    const float* x_proj_w  = (const float*)d_in[9];
    const float* dt_w      = (const float*)d_in[10];
    const float* dt_b      = (const float*)d_in[11];
    const float* A_log     = (const float*)d_in[12];
    const float* Dp        = (const float*)d_in[13];
    const float* out_proj_w= (const float*)d_in[14];

    float* out_main = (float*)d_out;                       // 2048*512
    float* rnn_out  = (float*)d_out + (size_t)BATCH * 512; // 2048*40960

    // Workspace layout (float offsets; peak 19,070,976 floats, same as before).
    float* ws = (float*)d_ws;
    float* xz     = ws;                                // [0, 8388608)
    u16*   ip_h   = (u16*)(ws + 8388608);              // 4,194,304 u16
    u16*   ip_l   = ip_h + 4194304;
    float* xc     = ws + 8388608;                      // reuse after K2
    u16*   core_h = (u16*)(ws + 8388608);              // reuse after K5
    u16*   core_l = core_h + 2097152;
    u16*   h_h    = (u16*)(ws + 12582912);
    u16*   h_l    = h_h + 2097152;
    u16*   x_h    = (u16*)(ws + 14680064);
    u16*   x_l    = x_h + 1048576;
    u16*   wi_h   = (u16*)(ws + 15728640);
    u16*   wi_l   = wi_h + 524288;
    u16*   y_h    = (u16*)(ws + 12582912);             // reuse after K2 (h,x,wi dead)
    u16*   y_l    = y_h + 4194304;
    u16*   op_h   = (u16*)(ws + 16777216);
    u16*   op_l   = op_h + 2097152;
    u16*   wo_h   = (u16*)(ws + 12582912);             // reuse after K6 (y dead)
    u16*   wo_l   = wo_h + 524288;
    float* xdb    = ws + 18874368;                     // 196,608

    // C0..C3: weight/input splits
    split_nt<<<1024, 256, 0, stream>>>(x, x_h, x_l, 262144);
    split_t <<<dim3(32, 16), 256, 0, stream>>>(w_inp, wi_h, wi_l, 512, 1024);
    split_nt<<<4096, 256, 0, stream>>>(in_proj_w, ip_h, ip_l, 1048576);
    split_nt<<<2048, 256, 0, stream>>>(out_proj_w, op_h, op_l, 524288);

    // K1: h = x @ w_inp + b_inp  -> h hi/lo
    gemm_mfma<true, true><<<dim3(8, 16), 256, 0, stream>>>(
        x_h, x_l, wi_h, wi_l, b_inp, nullptr, h_h, h_l, BATCH, 1024, 512);
    // K2: xz = h @ in_proj_w^T  -> fp32
    gemm_mfma<false, false><<<dim3(32, 16), 256, 0, stream>>>(
        h_h, h_l, ip_h, ip_l, nullptr, xz, nullptr, nullptr, BATCH, 4096, 1024);
    // K3: conv -> xc
    conv_kernel<<<(BATCH * D_INNER) / 256, 256, 0, stream>>>(
        rnn_in, xz, conv_w, conv_b, xc);
    // K4: xdb = xc @ x_proj_w^T
    xproj_kernel<<<BATCH / 8, 256, 0, stream>>>(xc, x_proj_w, xdb);
    // K5: ssm (fully parallel, writes full state rows) -> y hi/lo
    ssm2_kernel<<<dim3(D_INNER / 256, BATCH), 256, 0, stream>>>(
        rnn_in, xdb, xc, xz, dt_w, dt_b, A_log, Dp, y_h, y_l, rnn_out);
    // K6: core = y @ out_proj_w^T -> core hi/lo
    gemm_mfma<false, true><<<dim3(8, 16), 256, 0, stream>>>(
        y_h, y_l, op_h, op_l, nullptr, nullptr, core_h, core_l, BATCH, 1024, 2048);
    // C4: w_outp transpose+split (y region is dead now)
    split_t<<<dim3(16, 32), 256, 0, stream>>>(w_outp, wo_h, wo_l, 1024, 512);
    // K7: out = core @ w_outp + b_outp -> fp32
    gemm_mfma<true, false><<<dim3(4, 16), 256, 0, stream>>>(
        core_h, core_l, wo_h, wo_l, b_outp, out_main, nullptr, nullptr, BATCH, 512, 1024);
}

// Round 4
// 1191.851 us; speedup vs baseline: 1.5696x; 1.0154x over previous
//
#include <hip/hip_runtime.h>
#include <math.h>

// Mamba single-step recurrence, BATCH=2048.
// GEMMs run on the matrix cores via error-compensated split-bf16:
//   A = Ah + Al (bf16 hi/lo), B = Bh + Bl;  C = Ah*Bh + Al*Bh + Ah*Bl  (fp32 acc)
//
// Round 3 changes (memory-shape only, numerics identical):
//  - ssm3: state slab (256 d x 80B) staged coalesced through LDS both ways;
//    per-thread 20-float slot owned exclusively (stage -> bar -> compute in
//    own slot -> bar -> coalesced store). Kills the 80B-stride pattern that
//    held ssm2 at 1.85 TB/s.
//  - conv: same coalesced LDS staging for the state read.
//  - xproj: 2 batch rows/block, grid 1024 (was 256) -> 4 blocks/CU; LDS
//    x-values broadcast per wave (conflict-free).
// (Resubmitted verbatim after R3 GPU-acquisition timeout — no measurement yet.)

#define BATCH 2048
#define D_INNER 2048
#define D_STATE 16
#define D_CONV 4
#define DT_RANK 64
#define XDB_N 96
#define RNN_ROW 40960

typedef unsigned short u16;
typedef short bf16x8 __attribute__((ext_vector_type(8)));
typedef float f32x4 __attribute__((ext_vector_type(4)));

__device__ __forceinline__ float silu_f(float v) {
    return v / (1.f + __expf(-v));
}

// bf16 round-to-nearest-even, bit-level
__device__ __forceinline__ u16 f2bf(float x) {
    unsigned int u = __float_as_uint(x);
    u += 0x7FFFu + ((u >> 16) & 1u);
    return (u16)(u >> 16);
}
__device__ __forceinline__ float bf2f(u16 b) {
    return __uint_as_float(((unsigned int)b) << 16);
}
__device__ __forceinline__ void split_f(float x, u16& h, u16& l) {
    h = f2bf(x);
    l = f2bf(x - bf2f(h));
}

// async global->LDS, 16B per lane
typedef __attribute__((address_space(1))) const unsigned int guint;
typedef __attribute__((address_space(3))) unsigned int luint;
__device__ __forceinline__ void gload16(const void* g, void* l) {
    __builtin_amdgcn_global_load_lds((guint*)g, (luint*)l, 16, 0, 0);
}

// ---------------------------------------------------------------------------
// Split-bf16 MFMA GEMM: C[M,N] = (Ah+Al)[M,K] @ (Bh+Bl)[N,K]^T (+bias).
// 128x128 tile, BK=32, 256 threads (4 waves), 4x4 frags of 16x16x32 per wave.
// Double-buffered LDS, prefetch of tile t+1 overlaps MFMA of tile t, single
// barrier per K-step. XOR chunk-swizzle (slot ^= (row>>1)&3) on source+read.
// ---------------------------------------------------------------------------
template<bool BIAS, bool SPLITOUT>
__global__ __launch_bounds__(256)
void gemm_mfma(const u16* __restrict__ Ah, const u16* __restrict__ Al,
               const u16* __restrict__ Bh, const u16* __restrict__ Bl,
               const float* __restrict__ bias,
               float* __restrict__ Cf, u16* __restrict__ Ch, u16* __restrict__ Cl,
               int M, int N, int K) {
    __shared__ u16 sA_h[2][128 * 32];
    __shared__ u16 sA_l[2][128 * 32];
    __shared__ u16 sB_h[2][128 * 32];
    __shared__ u16 sB_l[2][128 * 32];

    const int tid  = threadIdx.x;
    const int wave = tid >> 6;
    const int lane = tid & 63;
    const int l16  = lane & 15;
    const int lsel = lane >> 4;

    // Bijective XCD-aware block swizzle (all grids have nwg % 8 == 0).
    int bx = blockIdx.x, by = blockIdx.y;
    {
        const int gx = gridDim.x;
        const int nwg = gx * gridDim.y;
        int bid = by * gx + bx;
        if ((nwg & 7) == 0) {
            bid = (bid & 7) * (nwg >> 3) + (bid >> 3);
            bx = bid % gx;
            by = bid / gx;
        }
    }
    const int m0 = by * 128;
    const int n0 = bx * 128;

    // staging: 128 rows x 32 bf16 (4 slots of 16B per row), LDS dest LINEAR in
    // chunk index; global source column chunk is XOR-swizzled.
    const int c0 = tid, c1 = tid + 256;
    const int sr0 = c0 >> 2, ss0 = ((c0 & 3) ^ ((sr0 >> 1) & 3)) * 8;
    const int sr1 = c1 >> 2, ss1 = ((c1 & 3) ^ ((sr1 >> 1) & 3)) * 8;
    const u16* gA0h = Ah + (size_t)(m0 + sr0) * K + ss0;
    const u16* gA1h = Ah + (size_t)(m0 + sr1) * K + ss1;
    const u16* gA0l = Al + (size_t)(m0 + sr0) * K + ss0;
    const u16* gA1l = Al + (size_t)(m0 + sr1) * K + ss1;
    const u16* gB0h = Bh + (size_t)(n0 + sr0) * K + ss0;
    const u16* gB1h = Bh + (size_t)(n0 + sr1) * K + ss1;
    const u16* gB0l = Bl + (size_t)(n0 + sr0) * K + ss0;
    const u16* gB1l = Bl + (size_t)(n0 + sr1) * K + ss1;
    const int l0 = c0 * 8, l1 = c1 * 8;  // u16 offsets (linear chunk layout)

    const int arow = (wave >> 1) * 64 + l16;
    const int brow = (wave & 1) * 64 + l16;
    const int swz  = (lsel ^ ((l16 >> 1) & 3)) * 8;

    f32x4 acc[4][4];
#pragma unroll
    for (int i = 0; i < 4; ++i)
#pragma unroll
        for (int j = 0; j < 4; ++j) acc[i][j] = f32x4{0.f, 0.f, 0.f, 0.f};

    auto stage = [&](int buf, int k0) {
        gload16(gA0h + k0, &sA_h[buf][l0]);
        gload16(gA1h + k0, &sA_h[buf][l1]);
        gload16(gA0l + k0, &sA_l[buf][l0]);
        gload16(gA1l + k0, &sA_l[buf][l1]);
        gload16(gB0h + k0, &sB_h[buf][l0]);
        gload16(gB1h + k0, &sB_h[buf][l1]);
        gload16(gB0l + k0, &sB_l[buf][l0]);
        gload16(gB1l + k0, &sB_l[buf][l1]);
    };

    int cur = 0;
    stage(0, 0);
    for (int k0 = 0; k0 < K; k0 += 32) {
        __syncthreads();                       // drains vmcnt -> buf[cur] ready
        if (k0 + 32 < K) stage(cur ^ 1, k0 + 32);  // prefetch overlaps MFMA

        bf16x8 bh[4], bl[4];
#pragma unroll
        for (int j = 0; j < 4; ++j) {
            bh[j] = *(const bf16x8*)&sB_h[cur][(brow + j * 16) * 32 + swz];
            bl[j] = *(const bf16x8*)&sB_l[cur][(brow + j * 16) * 32 + swz];
        }
#pragma unroll
        for (int i = 0; i < 4; ++i) {
            bf16x8 ah = *(const bf16x8*)&sA_h[cur][(arow + i * 16) * 32 + swz];
            bf16x8 al = *(const bf16x8*)&sA_l[cur][(arow + i * 16) * 32 + swz];
#pragma unroll
            for (int j = 0; j < 4; ++j) {
                acc[i][j] = __builtin_amdgcn_mfma_f32_16x16x32_bf16(ah, bh[j], acc[i][j], 0, 0, 0);
                acc[i][j] = __builtin_amdgcn_mfma_f32_16x16x32_bf16(al, bh[j], acc[i][j], 0, 0, 0);
                acc[i][j] = __builtin_amdgcn_mfma_f32_16x16x32_bf16(ah, bl[j], acc[i][j], 0, 0, 0);
            }
        }
        cur ^= 1;
    }

    // epilogue: C/D layout col = lane&15, row = (lane>>4)*4 + reg
    const int crow = m0 + (wave >> 1) * 64 + lsel * 4;
    const int ccol = n0 + (wave & 1) * 64 + l16;
#pragma unroll
    for (int i = 0; i < 4; ++i) {
#pragma unroll
        for (int j = 0; j < 4; ++j) {
            const int col = ccol + j * 16;
            float bv = 0.f;
            if (BIAS) bv = bias[col];
#pragma unroll
            for (int r = 0; r < 4; ++r) {
                const int row = crow + i * 16 + r;
                float v = acc[i][j][r] + bv;
                if (SPLITOUT) {
                    u16 hh, ll;
                    split_f(v, hh, ll);
                    Ch[(size_t)row * N + col] = hh;
                    Cl[(size_t)row * N + col] = ll;
                } else {
                    Cf[(size_t)row * N + col] = v;
                }
            }
        }
    }
}

// ---------------------------------------------------------------------------
// fp32 -> bf16 hi/lo splits
// ---------------------------------------------------------------------------
__global__ __launch_bounds__(256)
void split_nt(const float* __restrict__ W, u16* __restrict__ H, u16* __restrict__ L, int n4) {
    const int i = blockIdx.x * 256 + threadIdx.x;
    if (i >= n4) return;
    float4 v = ((const float4*)W)[i];
    u16 h0, l0, h1, l1, h2, l2, h3, l3;
    split_f(v.x, h0, l0); split_f(v.y, h1, l1);
    split_f(v.z, h2, l2); split_f(v.w, h3, l3);
    ushort4 hv; hv.x = h0; hv.y = h1; hv.z = h2; hv.w = h3;
    ushort4 lv; lv.x = l0; lv.y = l1; lv.z = l2; lv.w = l3;
    *(ushort4*)&H[(size_t)i * 4] = hv;
    *(ushort4*)&L[(size_t)i * 4] = lv;
}

// fp32 W[K][N] -> bf16 hi/lo [N][K] (transpose via 32x33 LDS tile)
__global__ __launch_bounds__(256)
void split_t(const float* __restrict__ W, u16* __restrict__ H, u16* __restrict__ L,
             int K, int N) {
    __shared__ float t[32][33];
    const int n0 = blockIdx.x * 32;
    const int k0 = blockIdx.y * 32;
    const int tx = threadIdx.x & 31;
    const int ty = threadIdx.x >> 5;   // 0..7
#pragma unroll
    for (int s = 0; s < 32; s += 8)
        t[ty + s][tx] = W[(size_t)(k0 + ty + s) * N + n0 + tx];
    __syncthreads();
#pragma unroll
    for (int s = 0; s < 32; s += 8) {
        float v = t[tx][ty + s];
        u16 h, l;
        split_f(v, h, l);
        H[(size_t)(n0 + ty + s) * K + k0 + tx] = h;
        L[(size_t)(n0 + ty + s) * K + k0 + tx] = l;
    }
}

// ---------------------------------------------------------------------------
// K3: depthwise conv + silu -> xc. State slab staged coalesced through LDS.
// Block = 256 consecutive d of one batch (20KB slab).
// ---------------------------------------------------------------------------
__global__ __launch_bounds__(256)
void conv_kernel(const float* __restrict__ rnn_in, const float* __restrict__ xz,
                 const float* __restrict__ conv_w, const float* __restrict__ conv_b,
                 float* __restrict__ xc) {
    __shared__ float row[5120];   // 256 d * 20 floats
    const int tid = threadIdx.x;
    const int b = blockIdx.y;
    const int d0 = blockIdx.x * 256;
    const float* src = rnn_in + (size_t)b * RNN_ROW + (size_t)d0 * 20;
#pragma unroll
    for (int i = 0; i < 5; ++i) {
        const int o = (i * 256 + tid) * 4;
        *(float4*)&row[o] = *(const float4*)&src[o];
    }
    __syncthreads();
    const int d = d0 + tid;
    const float c1 = row[tid * 20 + 1];
    const float c2 = row[tid * 20 + 2];
    const float c3 = row[tid * 20 + 3];
    const float xi = xz[(size_t)b * 4096 + d];
    const float4 w = *(const float4*)&conv_w[d * 4];
    const float pre = c1 * w.x + c2 * w.y + c3 * w.z + xi * w.w + conv_b[d];
    xc[(size_t)b * 2048 + d] = silu_f(pre);
}

// ---------------------------------------------------------------------------
// K4: xdb[b][n] = sum_k xc[b][k]*x_proj_w[n][k], n<96.
// 2 batch rows per block, grid 1024 (4 blocks/CU). LDS x-values broadcast.
// ---------------------------------------------------------------------------
__global__ __launch_bounds__(256)
void xproj_kernel(const float* __restrict__ xc, const float* __restrict__ xw,
                  float* __restrict__ xdb) {
    __shared__ float xsm[4096];
    const int tid = threadIdx.x;
    const int b0 = blockIdx.x * 2;
    const float* src = xc + (size_t)b0 * 2048;
#pragma unroll
    for (int i = 0; i < 4; ++i) {
        const int o = (i * 256 + tid) * 4;
        *(float4*)&xsm[o] = *(const float4*)&src[o];
    }
    __syncthreads();
    const int r = tid >> 7;     // 0..1
    const int n = tid & 127;    // lane's output column
    if (n < XDB_N) {
        const float* xr = &xsm[r * 2048];
        const float* wr = &xw[(size_t)n * 2048];
        float acc = 0.f;
#pragma unroll 4
        for (int k = 0; k < 2048; k += 4) {
            float4 xv = *(const float4*)&xr[k];
            float4 w  = *(const float4*)&wr[k];
            acc = fmaf(xv.x, w.x, fmaf(xv.y, w.y, fmaf(xv.z, w.z, fmaf(xv.w, w.w, acc))));
        }
        xdb[(size_t)(b0 + r) * XDB_N + n] = acc;
    }
}

// ---------------------------------------------------------------------------
// K5 (ssm3): one thread per (b,d); state slab staged coalesced through LDS
// both directions. Thread owns LDS slot [tid*20, tid*20+20) exclusively
// between the two barriers. Emits y as bf16 hi/lo.
// ---------------------------------------------------------------------------
__global__ __launch_bounds__(256)
void ssm3_kernel(const float* __restrict__ rnn_in, const float* __restrict__ xdb,
                 const float* __restrict__ xc, const float* __restrict__ xz,
                 const float* __restrict__ dt_w, const float* __restrict__ dt_b,
                 const float* __restrict__ A_log, const float* __restrict__ Dp,
                 u16* __restrict__ y_h, u16* __restrict__ y_l,
                 float* __restrict__ rnn_out) {
    __shared__ float row[5120];   // 256 d * 20 floats
    __shared__ float xs[XDB_N];
    const int tid = threadIdx.x;
    const int b = blockIdx.y;
    const int d0 = blockIdx.x * 256;
    const int d = d0 + tid;
    const float* src = rnn_in + (size_t)b * RNN_ROW + (size_t)d0 * 20;
    float* dst = rnn_out + (size_t)b * RNN_ROW + (size_t)d0 * 20;

#pragma unroll
    for (int i = 0; i < 5; ++i) {
        const int o = (i * 256 + tid) * 4;
        *(float4*)&row[o] = *(const float4*)&src[o];
    }
    if (tid < XDB_N) xs[tid] = xdb[(size_t)b * XDB_N + tid];
    __syncthreads();

    // own slot -> registers
    float st[20];
#pragma unroll
    for (int i = 0; i < 20; ++i) st[i] = row[tid * 20 + i];

    // dt = softplus(xdb[b,:64] . dt_w[d] + dt_b[d])   (dt_w row L2-resident)
    float acc = dt_b[d];
#pragma unroll
    for (int k = 0; k < 64; k += 4) {
        float4 w = *(const float4*)&dt_w[(size_t)d * 64 + k];
        acc = fmaf(xs[k], w.x, fmaf(xs[k + 1], w.y,
              fmaf(xs[k + 2], w.z, fmaf(xs[k + 3], w.w, acc))));
    }
    const float dt = (acc > 20.f) ? acc : log1pf(__expf(acc));

    const float xc_v = xc[(size_t)b * 2048 + d];
    const float xi   = xz[(size_t)b * 4096 + d];
    const float z_v  = xz[(size_t)b * 4096 + 2048 + d];
    const float dtxc = dt * xc_v;

    float al[16];
    *(float4*)&al[0]  = *(const float4*)&A_log[(size_t)d * 16 + 0];
    *(float4*)&al[4]  = *(const float4*)&A_log[(size_t)d * 16 + 4];
    *(float4*)&al[8]  = *(const float4*)&A_log[(size_t)d * 16 + 8];
    *(float4*)&al[12] = *(const float4*)&A_log[(size_t)d * 16 + 12];

    float out[20];
    out[0] = st[1]; out[1] = st[2]; out[2] = st[3]; out[3] = xi;
    float y_acc = Dp[d] * xc_v;
#pragma unroll
    for (int s = 0; s < 16; ++s) {
        float ns = fmaf(st[4 + s], __expf(dt * -__expf(al[s])), dtxc * xs[DT_RANK + s]);
        out[4 + s] = ns;
        y_acc = fmaf(ns, xs[DT_RANK + 16 + s], y_acc);
    }

    // write own slot back (exclusive ownership; no barrier needed vs reads)
#pragma unroll
    for (int i = 0; i < 20; ++i) row[tid * 20 + i] = out[i];
    __syncthreads();

#pragma unroll
    for (int i = 0; i < 5; ++i) {
        const int o = (i * 256 + tid) * 4;
        *(float4*)&dst[o] = *(const float4*)&row[o];
    }

    const float yv = y_acc * silu_f(z_v);
    u16 hh, ll;
    split_f(yv, hh, ll);
    const size_t yo = (size_t)b * 2048 + d;
    y_h[yo] = hh;
    y_l[yo] = ll;
}

// ---------------------------------------------------------------------------
extern "C" void kernel_launch(void* const* d_in, const int* in_sizes, int n_in,
                              void* d_out, int out_size, void* d_ws, size_t ws_size,
                              hipStream_t stream) {
    const float* x         = (const float*)d_in[0];
    const float* rnn_in    = (const float*)d_in[1];
    const float* w_inp     = (const float*)d_in[2];
    const float* b_inp     = (const float*)d_in[3];
    const float* w_outp    = (const float*)d_in[4];
    const float* b_outp    = (const float*)d_in[5];
    const float* in_proj_w = (const float*)d_in[6];
    const float* conv_w    = (const float*)d_in[7];
    const float* conv_b    = (const float*)d_in[8];
    const float* x_proj_w  = (const float*)d_in[9];
    const float* dt_w      = (const float*)d_in[10];
    const float* dt_b      = (const float*)d_in[11];
    const float* A_log     = (const float*)d_in[12];
    const float* Dp        = (const float*)d_in[13];
    const float* out_proj_w= (const float*)d_in[14];

    float* out_main = (float*)d_out;                       // 2048*512
    float* rnn_out  = (float*)d_out + (size_t)BATCH * 512; // 2048*40960

    // Workspace layout (float offsets; peak 19,070,976 floats).
    float* ws = (float*)d_ws;
    float* xz     = ws;                                // [0, 8388608)
    u16*   ip_h   = (u16*)(ws + 8388608);              // 4,194,304 u16
    u16*   ip_l   = ip_h + 4194304;
    float* xc     = ws + 8388608;                      // reuse after K2
    u16*   core_h = (u16*)(ws + 8388608);              // reuse after K5
    u16*   core_l = core_h + 2097152;
    u16*   h_h    = (u16*)(ws + 12582912);
    u16*   h_l    = h_h + 2097152;
    u16*   x_h    = (u16*)(ws + 14680064);
    u16*   x_l    = x_h + 1048576;
    u16*   wi_h   = (u16*)(ws + 15728640);
    u16*   wi_l   = wi_h + 524288;
    u16*   y_h    = (u16*)(ws + 12582912);             // reuse after K2 (h,x,wi dead)
    u16*   y_l    = y_h + 4194304;
    u16*   op_h   = (u16*)(ws + 16777216);
    u16*   op_l   = op_h + 2097152;
    u16*   wo_h   = (u16*)(ws + 12582912);             // reuse after K6 (y dead)
    u16*   wo_l   = wo_h + 524288;
    float* xdb    = ws + 18874368;                     // 196,608

    // C0..C3: weight/input splits
    split_nt<<<1024, 256, 0, stream>>>(x, x_h, x_l, 262144);
    split_t <<<dim3(32, 16), 256, 0, stream>>>(w_inp, wi_h, wi_l, 512, 1024);
    split_nt<<<4096, 256, 0, stream>>>(in_proj_w, ip_h, ip_l, 1048576);
    split_nt<<<2048, 256, 0, stream>>>(out_proj_w, op_h, op_l, 524288);

    // K1: h = x @ w_inp + b_inp  -> h hi/lo
    gemm_mfma<true, true><<<dim3(8, 16), 256, 0, stream>>>(
        x_h, x_l, wi_h, wi_l, b_inp, nullptr, h_h, h_l, BATCH, 1024, 512);
    // K2: xz = h @ in_proj_w^T  -> fp32
    gemm_mfma<false, false><<<dim3(32, 16), 256, 0, stream>>>(
        h_h, h_l, ip_h, ip_l, nullptr, xz, nullptr, nullptr, BATCH, 4096, 1024);
    // K3: conv -> xc (coalesced staged state read)
    conv_kernel<<<dim3(8, BATCH), 256, 0, stream>>>(
        rnn_in, xz, conv_w, conv_b, xc);
    // K4: xdb = xc @ x_proj_w^T
    xproj_kernel<<<BATCH / 2, 256, 0, stream>>>(xc, x_proj_w, xdb);
    // K5: ssm (coalesced staged state r/w) -> y hi/lo
    ssm3_kernel<<<dim3(8, BATCH), 256, 0, stream>>>(
        rnn_in, xdb, xc, xz, dt_w, dt_b, A_log, Dp, y_h, y_l, rnn_out);
    // K6: core = y @ out_proj_w^T -> core hi/lo
    gemm_mfma<false, true><<<dim3(8, 16), 256, 0, stream>>>(
        y_h, y_l, op_h, op_l, nullptr, nullptr, core_h, core_l, BATCH, 1024, 2048);
    // C4: w_outp transpose+split (y region is dead now)
    split_t<<<dim3(16, 32), 256, 0, stream>>>(w_outp, wo_h, wo_l, 1024, 512);
    // K7: out = core @ w_outp + b_outp -> fp32
    gemm_mfma<true, false><<<dim3(4, 16), 256, 0, stream>>>(
        core_h, core_l, wo_h, wo_l, b_outp, out_main, nullptr, nullptr, BATCH, 512, 1024);
}

// Round 13
// 1003.577 us; speedup vs baseline: 1.8641x; 1.1876x over previous
//
#include <hip/hip_runtime.h>
#include <math.h>

// Mamba single-step recurrence, BATCH=2048.
// GEMMs run on the matrix cores via error-compensated split-bf16:
//   A = Ah + Al (bf16 hi/lo), B = Bh + Bl;  C = Ah*Bh + Al*Bh + Ah*Bl  (fp32 acc)
//
// Round 5 changes (kill the L2-transaction bound in the middle section):
//  - ssm4: block owns d-chunk, walks 8 batches; dt_w/A_log/conv/D/dt_b held in
//    REGISTERS (once per block, was per-batch per-lane row reads = 5K txns/blk);
//    slab loads register-staged + software-pipelined (next slab in flight
//    during compute). Recomputes xc from its own slab (xc buffer eliminated).
//  - convproj: replaces conv_kernel + xproj_kernel. Computes xc for 4 batches
//    into LDS from strided 16B state reads, then the 96-wide projection with
//    COALESCED weight rows (wave-per-n, lanes split k, shuffle reduce).
// (Resubmitted verbatim after a ninth GPU-acquisition timeout — unmeasured.)

#define BATCH 2048
#define D_INNER 2048
#define D_STATE 16
#define D_CONV 4
#define DT_RANK 64
#define XDB_N 96
#define RNN_ROW 40960

typedef unsigned short u16;
typedef short bf16x8 __attribute__((ext_vector_type(8)));
typedef float f32x4 __attribute__((ext_vector_type(4)));

__device__ __forceinline__ float silu_f(float v) {
    return v / (1.f + __expf(-v));
}

// bf16 round-to-nearest-even, bit-level
__device__ __forceinline__ u16 f2bf(float x) {
    unsigned int u = __float_as_uint(x);
    u += 0x7FFFu + ((u >> 16) & 1u);
    return (u16)(u >> 16);
}
__device__ __forceinline__ float bf2f(u16 b) {
    return __uint_as_float(((unsigned int)b) << 16);
}
__device__ __forceinline__ void split_f(float x, u16& h, u16& l) {
    h = f2bf(x);
    l = f2bf(x - bf2f(h));
}

// async global->LDS, 16B per lane
typedef __attribute__((address_space(1))) const unsigned int guint;
typedef __attribute__((address_space(3))) unsigned int luint;
__device__ __forceinline__ void gload16(const void* g, void* l) {
    __builtin_amdgcn_global_load_lds((guint*)g, (luint*)l, 16, 0, 0);
}

// ---------------------------------------------------------------------------
// Split-bf16 MFMA GEMM: C[M,N] = (Ah+Al)[M,K] @ (Bh+Bl)[N,K]^T (+bias).
// 128x128 tile, BK=32, 256 threads (4 waves), 4x4 frags of 16x16x32 per wave.
// Double-buffered LDS, prefetch of tile t+1 overlaps MFMA of tile t, single
// barrier per K-step. XOR chunk-swizzle (slot ^= (row>>1)&3) on source+read.
// ---------------------------------------------------------------------------
template<bool BIAS, bool SPLITOUT>
__global__ __launch_bounds__(256)
void gemm_mfma(const u16* __restrict__ Ah, const u16* __restrict__ Al,
               const u16* __restrict__ Bh, const u16* __restrict__ Bl,
               const float* __restrict__ bias,
               float* __restrict__ Cf, u16* __restrict__ Ch, u16* __restrict__ Cl,
               int M, int N, int K) {
    __shared__ u16 sA_h[2][128 * 32];
    __shared__ u16 sA_l[2][128 * 32];
    __shared__ u16 sB_h[2][128 * 32];
    __shared__ u16 sB_l[2][128 * 32];

    const int tid  = threadIdx.x;
    const int wave = tid >> 6;
    const int lane = tid & 63;
    const int l16  = lane & 15;
    const int lsel = lane >> 4;

    // Bijective XCD-aware block swizzle (all grids have nwg % 8 == 0).
    int bx = blockIdx.x, by = blockIdx.y;
    {
        const int gx = gridDim.x;
        const int nwg = gx * gridDim.y;
        int bid = by * gx + bx;
        if ((nwg & 7) == 0) {
            bid = (bid & 7) * (nwg >> 3) + (bid >> 3);
            bx = bid % gx;
            by = bid / gx;
        }
    }
    const int m0 = by * 128;
    const int n0 = bx * 128;

    // staging: 128 rows x 32 bf16 (4 slots of 16B per row), LDS dest LINEAR in
    // chunk index; global source column chunk is XOR-swizzled.
    const int c0 = tid, c1 = tid + 256;
    const int sr0 = c0 >> 2, ss0 = ((c0 & 3) ^ ((sr0 >> 1) & 3)) * 8;
    const int sr1 = c1 >> 2, ss1 = ((c1 & 3) ^ ((sr1 >> 1) & 3)) * 8;
    const u16* gA0h = Ah + (size_t)(m0 + sr0) * K + ss0;
    const u16* gA1h = Ah + (size_t)(m0 + sr1) * K + ss1;
    const u16* gA0l = Al + (size_t)(m0 + sr0) * K + ss0;
    const u16* gA1l = Al + (size_t)(m0 + sr1) * K + ss1;
    const u16* gB0h = Bh + (size_t)(n0 + sr0) * K + ss0;
    const u16* gB1h = Bh + (size_t)(n0 + sr1) * K + ss1;
    const u16* gB0l = Bl + (size_t)(n0 + sr0) * K + ss0;
    const u16* gB1l = Bl + (size_t)(n0 + sr1) * K + ss1;
    const int l0 = c0 * 8, l1 = c1 * 8;  // u16 offsets (linear chunk layout)

    const int arow = (wave >> 1) * 64 + l16;
    const int brow = (wave & 1) * 64 + l16;
    const int swz  = (lsel ^ ((l16 >> 1) & 3)) * 8;

    f32x4 acc[4][4];
#pragma unroll
    for (int i = 0; i < 4; ++i)
#pragma unroll
        for (int j = 0; j < 4; ++j) acc[i][j] = f32x4{0.f, 0.f, 0.f, 0.f};

    auto stage = [&](int buf, int k0) {
        gload16(gA0h + k0, &sA_h[buf][l0]);
        gload16(gA1h + k0, &sA_h[buf][l1]);
        gload16(gA0l + k0, &sA_l[buf][l0]);
        gload16(gA1l + k0, &sA_l[buf][l1]);
        gload16(gB0h + k0, &sB_h[buf][l0]);
        gload16(gB1h + k0, &sB_h[buf][l1]);
        gload16(gB0l + k0, &sB_l[buf][l0]);
        gload16(gB1l + k0, &sB_l[buf][l1]);
    };

    int cur = 0;
    stage(0, 0);
    for (int k0 = 0; k0 < K; k0 += 32) {
        __syncthreads();                       // drains vmcnt -> buf[cur] ready
        if (k0 + 32 < K) stage(cur ^ 1, k0 + 32);  // prefetch overlaps MFMA

        bf16x8 bh[4], bl[4];
#pragma unroll
        for (int j = 0; j < 4; ++j) {
            bh[j] = *(const bf16x8*)&sB_h[cur][(brow + j * 16) * 32 + swz];
            bl[j] = *(const bf16x8*)&sB_l[cur][(brow + j * 16) * 32 + swz];
        }
#pragma unroll
        for (int i = 0; i < 4; ++i) {
            bf16x8 ah = *(const bf16x8*)&sA_h[cur][(arow + i * 16) * 32 + swz];
            bf16x8 al = *(const bf16x8*)&sA_l[cur][(arow + i * 16) * 32 + swz];
#pragma unroll
            for (int j = 0; j < 4; ++j) {
                acc[i][j] = __builtin_amdgcn_mfma_f32_16x16x32_bf16(ah, bh[j], acc[i][j], 0, 0, 0);
                acc[i][j] = __builtin_amdgcn_mfma_f32_16x16x32_bf16(al, bh[j], acc[i][j], 0, 0, 0);
                acc[i][j] = __builtin_amdgcn_mfma_f32_16x16x32_bf16(ah, bl[j], acc[i][j], 0, 0, 0);
            }
        }
        cur ^= 1;
    }

    // epilogue: C/D layout col = lane&15, row = (lane>>4)*4 + reg
    const int crow = m0 + (wave >> 1) * 64 + lsel * 4;
    const int ccol = n0 + (wave & 1) * 64 + l16;
#pragma unroll
    for (int i = 0; i < 4; ++i) {
#pragma unroll
        for (int j = 0; j < 4; ++j) {
            const int col = ccol + j * 16;
            float bv = 0.f;
            if (BIAS) bv = bias[col];
#pragma unroll
            for (int r = 0; r < 4; ++r) {
                const int row = crow + i * 16 + r;
                float v = acc[i][j][r] + bv;
                if (SPLITOUT) {
                    u16 hh, ll;
                    split_f(v, hh, ll);
                    Ch[(size_t)row * N + col] = hh;
                    Cl[(size_t)row * N + col] = ll;
                } else {
                    Cf[(size_t)row * N + col] = v;
                }
            }
        }
    }
}

// ---------------------------------------------------------------------------
// fp32 -> bf16 hi/lo splits
// ---------------------------------------------------------------------------
__global__ __launch_bounds__(256)
void split_nt(const float* __restrict__ W, u16* __restrict__ H, u16* __restrict__ L, int n4) {
    const int i = blockIdx.x * 256 + threadIdx.x;
    if (i >= n4) return;
    float4 v = ((const float4*)W)[i];
    u16 h0, l0, h1, l1, h2, l2, h3, l3;
    split_f(v.x, h0, l0); split_f(v.y, h1, l1);
    split_f(v.z, h2, l2); split_f(v.w, h3, l3);
    ushort4 hv; hv.x = h0; hv.y = h1; hv.z = h2; hv.w = h3;
    ushort4 lv; lv.x = l0; lv.y = l1; lv.z = l2; lv.w = l3;
    *(ushort4*)&H[(size_t)i * 4] = hv;
    *(ushort4*)&L[(size_t)i * 4] = lv;
}

// fp32 W[K][N] -> bf16 hi/lo [N][K] (transpose via 32x33 LDS tile)
__global__ __launch_bounds__(256)
void split_t(const float* __restrict__ W, u16* __restrict__ H, u16* __restrict__ L,
             int K, int N) {
    __shared__ float t[32][33];
    const int n0 = blockIdx.x * 32;
    const int k0 = blockIdx.y * 32;
    const int tx = threadIdx.x & 31;
    const int ty = threadIdx.x >> 5;   // 0..7
#pragma unroll
    for (int s = 0; s < 32; s += 8)
        t[ty + s][tx] = W[(size_t)(k0 + ty + s) * N + n0 + tx];
    __syncthreads();
#pragma unroll
    for (int s = 0; s < 32; s += 8) {
        float v = t[tx][ty + s];
        u16 h, l;
        split_f(v, h, l);
        H[(size_t)(n0 + ty + s) * K + k0 + tx] = h;
        L[(size_t)(n0 + ty + s) * K + k0 + tx] = l;
    }
}

// ---------------------------------------------------------------------------
// convproj: replaces conv + xproj. Block handles 4 batches, ALL 2048 d.
// Phase 1: xc[bb][d] = silu(conv) from strided 16B state reads (floats 0..3
//          of each 80B row) + xi from xz. Stored in LDS only.
// Phase 2: xdb[b][n] = sum_k xc[b][k]*xw[n][k]; wave-per-n, lanes split k
//          (weight rows read COALESCED), butterfly shuffle reduce.
// ---------------------------------------------------------------------------
__global__ __launch_bounds__(256)
void convproj_kernel(const float* __restrict__ rnn_in, const float* __restrict__ xz,
                     const float* __restrict__ conv_w, const float* __restrict__ conv_b,
                     const float* __restrict__ xw, float* __restrict__ xdb) {
    __shared__ float xc[4][2048];
    const int tid = threadIdx.x;
    const int b0 = blockIdx.x * 4;
#pragma unroll
    for (int bb = 0; bb < 4; ++bb) {
        const int b = b0 + bb;
#pragma unroll
        for (int k = 0; k < 8; ++k) {
            const int dd = k * 256 + tid;
            float4 cs = *(const float4*)&rnn_in[(size_t)b * RNN_ROW + (size_t)dd * 20];
            const float xi = xz[(size_t)b * 4096 + dd];
            const float4 w = *(const float4*)&conv_w[dd * 4];
            const float pre = cs.y * w.x + cs.z * w.y + cs.w * w.z + xi * w.w + conv_b[dd];
            xc[bb][dd] = silu_f(pre);
        }
    }
    __syncthreads();
    const int wave = tid >> 6;
    const int lane = tid & 63;
    for (int j = 0; j < 24; ++j) {
        const int n = j * 4 + wave;
        const float* wr = &xw[(size_t)n * 2048];
        float a0 = 0.f, a1 = 0.f, a2 = 0.f, a3 = 0.f;
#pragma unroll
        for (int it = 0; it < 8; ++it) {
            const int k4 = (it * 64 + lane) * 4;
            float4 wv = *(const float4*)&wr[k4];
            float4 x0 = *(const float4*)&xc[0][k4];
            float4 x1 = *(const float4*)&xc[1][k4];
            float4 x2 = *(const float4*)&xc[2][k4];
            float4 x3 = *(const float4*)&xc[3][k4];
            a0 = fmaf(wv.x, x0.x, fmaf(wv.y, x0.y, fmaf(wv.z, x0.z, fmaf(wv.w, x0.w, a0))));
            a1 = fmaf(wv.x, x1.x, fmaf(wv.y, x1.y, fmaf(wv.z, x1.z, fmaf(wv.w, x1.w, a1))));
            a2 = fmaf(wv.x, x2.x, fmaf(wv.y, x2.y, fmaf(wv.z, x2.z, fmaf(wv.w, x2.w, a2))));
            a3 = fmaf(wv.x, x3.x, fmaf(wv.y, x3.y, fmaf(wv.z, x3.z, fmaf(wv.w, x3.w, a3))));
        }
#pragma unroll
        for (int m = 32; m > 0; m >>= 1) {
            a0 += __shfl_xor(a0, m);
            a1 += __shfl_xor(a1, m);
            a2 += __shfl_xor(a2, m);
            a3 += __shfl_xor(a3, m);
        }
        if (lane == 0) {
            xdb[(size_t)(b0 + 0) * XDB_N + n] = a0;
            xdb[(size_t)(b0 + 1) * XDB_N + n] = a1;
            xdb[(size_t)(b0 + 2) * XDB_N + n] = a2;
            xdb[(size_t)(b0 + 3) * XDB_N + n] = a3;
        }
    }
}

// ---------------------------------------------------------------------------
// ssm4: block owns d-chunk (256 d), walks 8 batches. Per-thread parameters
// (dt_w row, A_row, conv_w/b, D, dt_b) live in registers for all 8 batches.
// State slab register-staged + pipelined: slab(b+1) loads issued before the
// compute of slab(b). xc recomputed in-kernel from the slab (no xc buffer).
// Coalesced LDS-transposed slab store both directions. Emits y bf16 hi/lo.
// ---------------------------------------------------------------------------
__global__ __launch_bounds__(256, 3)
void ssm4_kernel(const float* __restrict__ rnn_in, const float* __restrict__ xdb,
                 const float* __restrict__ xz,
                 const float* __restrict__ dt_w, const float* __restrict__ dt_b,
                 const float* __restrict__ A_log, const float* __restrict__ Dp,
                 const float* __restrict__ conv_w, const float* __restrict__ conv_b,
                 u16* __restrict__ y_h, u16* __restrict__ y_l,
                 float* __restrict__ rnn_out) {
    __shared__ float slab[5120];   // 256 d * 20 floats
    __shared__ float xs[XDB_N];
    const int tid = threadIdx.x;
    const int d0 = blockIdx.x * 256;
    const int b0 = blockIdx.y * 8;
    const int d  = d0 + tid;

    // per-thread persistent parameters (amortized over 8 batches)
    float4 wreg[16];
#pragma unroll
    for (int j = 0; j < 16; ++j)
        wreg[j] = *(const float4*)&dt_w[(size_t)d * 64 + j * 4];
    float A_row[16];
    {
        float al[16];
        *(float4*)&al[0]  = *(const float4*)&A_log[(size_t)d * 16 + 0];
        *(float4*)&al[4]  = *(const float4*)&A_log[(size_t)d * 16 + 4];
        *(float4*)&al[8]  = *(const float4*)&A_log[(size_t)d * 16 + 8];
        *(float4*)&al[12] = *(const float4*)&A_log[(size_t)d * 16 + 12];
#pragma unroll
        for (int s = 0; s < 16; ++s) A_row[s] = -__expf(al[s]);
    }
    const float4 cw  = *(const float4*)&conv_w[d * 4];
    const float  cb  = conv_b[d];
    const float  D_d = Dp[d];
    const float  dtb = dt_b[d];

    // prologue: stage slab(b0) into regs
    float4 rs[5];
    {
        const float* src = rnn_in + (size_t)b0 * RNN_ROW + (size_t)d0 * 20;
#pragma unroll
        for (int i = 0; i < 5; ++i) rs[i] = *(const float4*)&src[(i * 256 + tid) * 4];
    }
    float xv = 0.f;
    if (tid < XDB_N) xv = xdb[(size_t)b0 * XDB_N + tid];

    for (int g = 0; g < 8; ++g) {
        const int b = b0 + g;
        __syncthreads();   // B1: prev iteration's LDS consumers done
#pragma unroll
        for (int i = 0; i < 5; ++i) *(float4*)&slab[(i * 256 + tid) * 4] = rs[i];
        if (tid < XDB_N) xs[tid] = xv;
        __syncthreads();   // B2: slab + xs visible

        // this-iteration scalar loads BEFORE the next-slab prefetch, so the
        // compiler's waits for them don't drain the prefetch.
        const float xi = xz[(size_t)b * 4096 + d];
        const float zv = xz[(size_t)b * 4096 + 2048 + d];
        if (g < 7) {
            const float* srcn = rnn_in + (size_t)(b + 1) * RNN_ROW + (size_t)d0 * 20;
#pragma unroll
            for (int i = 0; i < 5; ++i) rs[i] = *(const float4*)&srcn[(i * 256 + tid) * 4];
            if (tid < XDB_N) xv = xdb[(size_t)(b + 1) * XDB_N + tid];
        }

        // own 20-float slot -> regs
        float st[20];
#pragma unroll
        for (int i = 0; i < 5; ++i)
            *(float4*)&st[i * 4] = *(const float4*)&slab[tid * 20 + i * 4];

        // conv + silu (xc recompute)
        const float pre  = st[1] * cw.x + st[2] * cw.y + st[3] * cw.z + xi * cw.w + cb;
        const float xc_v = silu_f(pre);

        // dt = softplus(xs[0:64] . wreg + dtb)
        float acc = dtb;
#pragma unroll
        for (int j = 0; j < 16; ++j) {
            acc = fmaf(xs[j * 4 + 0], wreg[j].x,
                  fmaf(xs[j * 4 + 1], wreg[j].y,
                  fmaf(xs[j * 4 + 2], wreg[j].z,
                  fmaf(xs[j * 4 + 3], wreg[j].w, acc))));
        }
        const float dt   = (acc > 20.f) ? acc : log1pf(__expf(acc));
        const float dtxc = dt * xc_v;

        float y_acc = D_d * xc_v;
#pragma unroll
        for (int s = 0; s < 16; ++s) {
            float ns = fmaf(st[4 + s], __expf(dt * A_row[s]), dtxc * xs[DT_RANK + s]);
            st[4 + s] = ns;
            y_acc = fmaf(ns, xs[DT_RANK + 16 + s], y_acc);
        }
        // conv shift in place (ascending order keeps values correct)
        st[0] = st[1]; st[1] = st[2]; st[2] = st[3]; st[3] = xi;

        // own slot write-back (exclusive; no cross-thread reads until B3)
#pragma unroll
        for (int i = 0; i < 5; ++i)
            *(float4*)&slab[tid * 20 + i * 4] = *(const float4*)&st[i * 4];
        __syncthreads();   // B3: all slots updated

        float* dst = rnn_out + (size_t)b * RNN_ROW + (size_t)d0 * 20;
#pragma unroll
        for (int i = 0; i < 5; ++i)
            *(float4*)&dst[(i * 256 + tid) * 4] = *(const float4*)&slab[(i * 256 + tid) * 4];

        const float yv = y_acc * silu_f(zv);
        u16 hh, ll;
        split_f(yv, hh, ll);
        y_h[(size_t)b * 2048 + d] = hh;
        y_l[(size_t)b * 2048 + d] = ll;
    }
}

// ---------------------------------------------------------------------------
extern "C" void kernel_launch(void* const* d_in, const int* in_sizes, int n_in,
                              void* d_out, int out_size, void* d_ws, size_t ws_size,
                              hipStream_t stream) {
    const float* x         = (const float*)d_in[0];
    const float* rnn_in    = (const float*)d_in[1];
    const float* w_inp     = (const float*)d_in[2];
    const float* b_inp     = (const float*)d_in[3];
    const float* w_outp    = (const float*)d_in[4];
    const float* b_outp    = (const float*)d_in[5];
    const float* in_proj_w = (const float*)d_in[6];
    const float* conv_w    = (const float*)d_in[7];
    const float* conv_b    = (const float*)d_in[8];
    const float* x_proj_w  = (const float*)d_in[9];
    const float* dt_w      = (const float*)d_in[10];
    const float* dt_b      = (const float*)d_in[11];
    const float* A_log     = (const float*)d_in[12];
    const float* Dp        = (const float*)d_in[13];
    const float* out_proj_w= (const float*)d_in[14];

    float* out_main = (float*)d_out;                       // 2048*512
    float* rnn_out  = (float*)d_out + (size_t)BATCH * 512; // 2048*40960

    // Workspace layout (float offsets; peak 19,070,976 floats).
    float* ws = (float*)d_ws;
    float* xz     = ws;                                // [0, 8388608)
    u16*   ip_h   = (u16*)(ws + 8388608);              // 4,194,304 u16
    u16*   ip_l   = ip_h + 4194304;
    u16*   core_h = (u16*)(ws + 8388608);              // reuse after K5
    u16*   core_l = core_h + 2097152;
    u16*   h_h    = (u16*)(ws + 12582912);
    u16*   h_l    = h_h + 2097152;
    u16*   x_h    = (u16*)(ws + 14680064);
    u16*   x_l    = x_h + 1048576;
    u16*   wi_h   = (u16*)(ws + 15728640);
    u16*   wi_l   = wi_h + 524288;
    u16*   y_h    = (u16*)(ws + 12582912);             // reuse after K2 (h,x,wi dead)
    u16*   y_l    = y_h + 4194304;
    u16*   op_h   = (u16*)(ws + 16777216);
    u16*   op_l   = op_h + 2097152;
    u16*   wo_h   = (u16*)(ws + 12582912);             // reuse after K6 (y dead)
    u16*   wo_l   = wo_h + 524288;
    float* xdb    = ws + 18874368;                     // 196,608

    // C0..C3: weight/input splits
    split_nt<<<1024, 256, 0, stream>>>(x, x_h, x_l, 262144);
    split_t <<<dim3(32, 16), 256, 0, stream>>>(w_inp, wi_h, wi_l, 512, 1024);
    split_nt<<<4096, 256, 0, stream>>>(in_proj_w, ip_h, ip_l, 1048576);
    split_nt<<<2048, 256, 0, stream>>>(out_proj_w, op_h, op_l, 524288);

    // K1: h = x @ w_inp + b_inp  -> h hi/lo
    gemm_mfma<true, true><<<dim3(8, 16), 256, 0, stream>>>(
        x_h, x_l, wi_h, wi_l, b_inp, nullptr, h_h, h_l, BATCH, 1024, 512);
    // K2: xz = h @ in_proj_w^T  -> fp32
    gemm_mfma<false, false><<<dim3(32, 16), 256, 0, stream>>>(
        h_h, h_l, ip_h, ip_l, nullptr, xz, nullptr, nullptr, BATCH, 4096, 1024);
    // K3+K4 fused: xc (LDS-only) + xdb
    convproj_kernel<<<BATCH / 4, 256, 0, stream>>>(
        rnn_in, xz, conv_w, conv_b, x_proj_w, xdb);
    // K5: ssm (pipelined, params in regs) -> y hi/lo + full state rows
    ssm4_kernel<<<dim3(8, BATCH / 8), 256, 0, stream>>>(
        rnn_in, xdb, xz, dt_w, dt_b, A_log, Dp, conv_w, conv_b, y_h, y_l, rnn_out);
    // K6: core = y @ out_proj_w^T -> core hi/lo
    gemm_mfma<false, true><<<dim3(8, 16), 256, 0, stream>>>(
        y_h, y_l, op_h, op_l, nullptr, nullptr, core_h, core_l, BATCH, 1024, 2048);
    // C4: w_outp transpose+split (y region is dead now)
    split_t<<<dim3(16, 32), 256, 0, stream>>>(w_outp, wo_h, wo_l, 1024, 512);
    // K7: out = core @ w_outp + b_outp -> fp32
    gemm_mfma<true, false><<<dim3(4, 16), 256, 0, stream>>>(
        core_h, core_l, wo_h, wo_l, b_outp, out_main, nullptr, nullptr, BATCH, 512, 1024);
}